// Round 11
// baseline (310.723 us; speedup 1.0000x reference)
//
#include <hip/hip_runtime.h>
#include <hip/hip_bf16.h>
#include <math.h>

// ---------------------------------------------------------------------------
// MultiheadAttention: B=2, S=2048, D_MODEL=1024, H=16, DK=DV=64
// outputs: out (B,S,1024) f32  then attns (H*B, S, S) f32, concatenated.
//
// MFMA conventions (v_mfma_f32_16x16x32_bf16):
//   A-frag: lane holds row i = lane&15, k = 8*(lane>>4)+e  (8 contiguous bf16)
//   B-frag: lane holds col j = lane&15, k = 8*(lane>>4)+e
//   C/D   : lane holds col j = lane&15, row i = 4*(lane>>4)+r   [HW-verified]
//
// R11: attn2 store-pattern experiment. R10 showed attn2 pinned at ~3.7 TB/s
// across 64B/128B/256B store shapes -> short strided runs are the suspect.
// Now: batch W=4 tiles of bf16 P in LDS (64 KB), flush once per batch as
// 1 KB CONTIGUOUS f32 row-runs (one row per wave-instruction), NT stores.
// ---------------------------------------------------------------------------

typedef __attribute__((ext_vector_type(8))) short short8;
typedef __attribute__((ext_vector_type(4))) float f32x4;
typedef __attribute__((ext_vector_type(4))) unsigned short ushort4v;

#define MFMA16(a, b, c) __builtin_amdgcn_mfma_f32_16x16x32_bf16(a, b, c, 0, 0, 0)
#define EXP2F(x) __builtin_amdgcn_exp2f(x)
#define LOG2F(x) __builtin_amdgcn_logf(x)

// raw barrier with counted vmem wait: N youngest vmem ops may stay outstanding
#define TILE_BARRIER(N) \
  asm volatile("s_waitcnt vmcnt(" #N ")\n\ts_barrier" ::: "memory")

static __device__ __forceinline__ unsigned short f2bf(float x) {
  unsigned int u = __float_as_uint(x);
  u += 0x7fffu + ((u >> 16) & 1u);  // RNE
  return (unsigned short)(u >> 16);
}
static __device__ __forceinline__ unsigned int pack2bf(float a, float b) {
  return (unsigned int)f2bf(a) | ((unsigned int)f2bf(b) << 16);
}

// async global->LDS, 16B per lane; LDS dest must be linear (wave base + lane*16)
static __device__ __forceinline__ void gload16(const unsigned short* g, unsigned short* l) {
  __builtin_amdgcn_global_load_lds(
      (const __attribute__((address_space(1))) unsigned int*)g,
      (__attribute__((address_space(3))) unsigned int*)l, 16, 0, 0);
}

// ---- convert f32 -> bf16: q,k,v,proj_w fused in one launch ----------------
__global__ void k_cvt_all(const float* __restrict__ q, const float* __restrict__ k,
                          const float* __restrict__ v, const float* __restrict__ pw,
                          unsigned short* __restrict__ qb, unsigned short* __restrict__ kb,
                          unsigned short* __restrict__ vb, unsigned short* __restrict__ pwb) {
  const int i = blockIdx.x * blockDim.x + threadIdx.x;  // float4 index
  const int N1 = 1048576;  // 4M elems / 4 per q/k/v buffer
  const float* s;
  unsigned short* d;
  int off;
  if (i < N1) { s = q; d = qb; off = i; }
  else if (i < 2 * N1) { s = k; d = kb; off = i - N1; }
  else if (i < 3 * N1) { s = v; d = vb; off = i - 2 * N1; }
  else { s = pw; d = pwb; off = i - 3 * N1; }
  float4 vv = reinterpret_cast<const float4*>(s)[off];
  ushort4v o;
  o.x = f2bf(vv.x); o.y = f2bf(vv.y); o.z = f2bf(vv.z); o.w = f2bf(vv.w);
  reinterpret_cast<ushort4v*>(d)[off] = o;
}

// ---- transpose-convert head weights via LDS tile --------------------------
// src [16][1024][64] f32 -> dst [16][64][1024] bf16 ; W_q pre-scaled by log2e/32
__global__ __launch_bounds__(256) void k_wt2(
    const float* __restrict__ s0, const float* __restrict__ s1, const float* __restrict__ s2,
    unsigned short* __restrict__ d0, unsigned short* __restrict__ d1,
    unsigned short* __restrict__ d2) {
  __shared__ float t[64][65];
  const int z = blockIdx.z;
  const float* __restrict__ s = (z == 0) ? s0 : ((z == 1) ? s1 : s2);
  unsigned short* __restrict__ d = (z == 0) ? d0 : ((z == 1) ? d1 : d2);
  const float wscale = (z == 0) ? 0.04508422002778011f : 1.0f;  // log2(e)/sqrt(1024)
  const int tid = threadIdx.x;
  const int h = blockIdx.y;
  const int dd0 = blockIdx.x * 64;
  const float* sp = s + ((size_t)h << 16);
  unsigned short* dp = d + ((size_t)h << 16);
#pragma unroll
  for (int it = 0; it < 16; ++it) {
    int dd = it * 4 + (tid >> 6);
    t[dd][tid & 63] = sp[(size_t)(dd0 + dd) * 64 + (tid & 63)];
  }
  __syncthreads();
#pragma unroll
  for (int it = 0; it < 16; ++it) {
    int kk = it * 4 + (tid >> 6);
    int dd = tid & 63;
    dp[(size_t)kk * 1024 + dd0 + dd] = f2bf(t[dd][kk] * wscale);
  }
}

// ---- projection GEMMs: 128x128 tile, LDS double-buffered ------------------
// qs/ks row-major [h][b][s][64], vs transposed [h][b][64][s]
__global__ __launch_bounds__(256, 3) void k_proj(
    const unsigned short* __restrict__ qb, const unsigned short* __restrict__ kb,
    const unsigned short* __restrict__ vb,
    const unsigned short* __restrict__ wqt, const unsigned short* __restrict__ wkt,
    const unsigned short* __restrict__ wvt,
    unsigned short* __restrict__ qs, unsigned short* __restrict__ ks,
    unsigned short* __restrict__ vst) {
  __shared__ unsigned short lA[2][4][128][8];  // 16 KB
  __shared__ unsigned short lB[2][4][128][8];  // 16 KB

  const int mode = blockIdx.z;
  const unsigned short* __restrict__ A = (mode == 0) ? qb : ((mode == 1) ? kb : vb);
  const unsigned short* __restrict__ W = (mode == 0) ? wqt : ((mode == 1) ? wkt : wvt);

  const int tid = threadIdx.x;
  const int wv = tid >> 6, lane = tid & 63, lq = lane & 15, g = lane >> 4;
  const int wr = wv >> 1, wc = wv & 1;
  const int m0 = blockIdx.x * 128;
  const int n0 = blockIdx.y * 128;

  const int rowm = tid & 127, kg = tid >> 7;
  const unsigned short* srcA = A + (size_t)(m0 + rowm) * 1024 + kg * 8;
  const unsigned short* srcB = W + (size_t)(n0 + rowm) * 1024 + kg * 8;
  unsigned short* dstA = &lA[0][0][0][0] + tid * 8;
  unsigned short* dstB = &lB[0][0][0][0] + tid * 8;

#define STAGE(bf, kc)                                       \
  do {                                                      \
    gload16(srcA + (kc), dstA + (bf)*4096);                 \
    gload16(srcA + (kc) + 16, dstA + (bf)*4096 + 2048);     \
    gload16(srcB + (kc), dstB + (bf)*4096);                 \
    gload16(srcB + (kc) + 16, dstB + (bf)*4096 + 2048);     \
  } while (0)

  f32x4 acc[4][4];
#pragma unroll
  for (int i = 0; i < 4; ++i)
#pragma unroll
    for (int j = 0; j < 4; ++j) acc[i][j] = (f32x4){0.f, 0.f, 0.f, 0.f};

  STAGE(0, 0);
  __syncthreads();
  for (int t = 0; t < 32; ++t) {
    const int buf = t & 1;
    if (t < 31) STAGE(buf ^ 1, (t + 1) * 32);
    short8 a[4], b[4];
#pragma unroll
    for (int i = 0; i < 4; ++i)
      a[i] = *reinterpret_cast<const short8*>(&lA[buf][g][wr * 64 + i * 16 + lq][0]);
#pragma unroll
    for (int j = 0; j < 4; ++j)
      b[j] = *reinterpret_cast<const short8*>(&lB[buf][g][wc * 64 + j * 16 + lq][0]);
#pragma unroll
    for (int i = 0; i < 4; ++i)
#pragma unroll
      for (int j = 0; j < 4; ++j) acc[i][j] = MFMA16(a[i], b[j], acc[i][j]);
    __syncthreads();
  }
#undef STAGE

#pragma unroll
  for (int i = 0; i < 4; ++i) {
#pragma unroll
    for (int j = 0; j < 4; ++j) {
      const int n = n0 + wc * 64 + j * 16 + lq;
      const int h = n >> 6, dk = n & 63;
#pragma unroll
      for (int r = 0; r < 4; ++r) {
        const int m = m0 + wr * 64 + i * 16 + g * 4 + r;
        const int b_ = m >> 11, sq = m & 2047;
        const unsigned short val = f2bf(acc[i][j][r]);
        if (mode == 0)
          qs[(((size_t)h * 2 + b_) * 2048 + sq) * 64 + dk] = val;
        else if (mode == 1)
          ks[(((size_t)h * 2 + b_) * 2048 + sq) * 64 + dk] = val;
        else
          vst[(((size_t)h * 2 + b_) * 64 + dk) * 2048 + sq] = val;
      }
    }
  }
}

// ---- attention sweep 1: softmax log-denominator per q row -----------------
// 512 blocks XCD-pinned; block = 4 waves x 32 q rows (2 subtiles share K reads)
__global__ __launch_bounds__(256, 2) void k_attn1(
    const unsigned short* __restrict__ qs, const unsigned short* __restrict__ ks,
    float* __restrict__ cf) {
  __shared__ unsigned short lk[2][4096];  // K tile [64 rows][64 d], swizzled cols

  const int tid = threadIdx.x;
  const int wv = tid >> 6, lane = tid & 63, lq = lane & 15, g = lane >> 4;
  const int bid = blockIdx.x;
  const int xcd = bid & 7, j = bid >> 3;     // j 0..63
  const int hb = xcd * 4 + (j & 3);
  const int qblk = j >> 2;                   // 0..15
  const int q0 = qblk * 128 + wv * 32;       // wave's 32-row base

  const unsigned short* __restrict__ Q = qs + (size_t)hb * 2048 * 64;
  const unsigned short* __restrict__ K = ks + (size_t)hb * 2048 * 64;

  short8 bq[2][2];
#pragma unroll
  for (int s = 0; s < 2; ++s) {
    const size_t qr = (size_t)(q0 + s * 16 + lq) * 64;
    bq[s][0] = *reinterpret_cast<const short8*>(Q + qr + g * 8);
    bq[s][1] = *reinterpret_cast<const short8*>(Q + qr + 32 + g * 8);
  }

  const int srow = tid >> 3;
  const int scg = (tid & 7) ^ (srow & 7);
  const unsigned short* Ks0 = K + (size_t)srow * 64 + scg * 8;
  const unsigned short* Ks1 = K + (size_t)(srow + 32) * 64 + scg * 8;

#define STAGE_K(bf, kt0)                                   \
  do {                                                     \
    gload16(Ks0 + (size_t)(kt0) * 64, &lk[bf][tid * 8]);   \
    gload16(Ks1 + (size_t)(kt0) * 64, &lk[bf][(tid + 256) * 8]); \
  } while (0)

  float lrun[2] = {0.f, 0.f};
  STAGE_K(0, 0);
  TILE_BARRIER(0);
  for (int t = 0; t < 32; ++t) {
    const int buf = t & 1;
    if (t < 31) STAGE_K(buf ^ 1, (t + 1) * 64);
#pragma unroll
    for (int sub = 0; sub < 4; ++sub) {
      const int row = sub * 16 + lq;
      const int c0 = g ^ (row & 7);
      const unsigned short* lp = &lk[buf][row * 64];
      short8 ka0 = *reinterpret_cast<const short8*>(lp + c0 * 8);
      short8 ka1 = *reinterpret_cast<const short8*>(lp + (c0 ^ 4) * 8);
#pragma unroll
      for (int s = 0; s < 2; ++s) {
        f32x4 sa = (f32x4){0.f, 0.f, 0.f, 0.f};
        sa = MFMA16(ka0, bq[s][0], sa);
        sa = MFMA16(ka1, bq[s][1], sa);  // log2 units (W_q pre-scaled)
        lrun[s] += (EXP2F(sa[0]) + EXP2F(sa[1])) + (EXP2F(sa[2]) + EXP2F(sa[3]));
      }
    }
    TILE_BARRIER(0);
  }
#pragma unroll
  for (int s = 0; s < 2; ++s) {
    float lc = lrun[s] + __shfl_xor(lrun[s], 16);
    lc += __shfl_xor(lc, 32);
    if (g == 0) cf[hb * 2048 + q0 + s * 16 + lq] = LOG2F(lc);
  }
#undef STAGE_K
}

// ---- attention sweep 2: W=4 tile-batched P, 1KB-run NT flush, PV ----------
__global__ __launch_bounds__(256, 1) void k_attn2(
    const unsigned short* __restrict__ qs, const unsigned short* __restrict__ ks,
    const unsigned short* __restrict__ vst, const float* __restrict__ cf,
    float* __restrict__ attns, unsigned short* __restrict__ att_out) {
  __shared__ unsigned short lk[2][4096];     // K tile, 16 KB
  __shared__ unsigned short lv[2][4096];     // V^T tile, 16 KB
  __shared__ unsigned char pscr[4][32][512]; // per-wave P, 4 tiles x 32 rows, 64 KB

  const int tid = threadIdx.x;
  const int wv = tid >> 6, lane = tid & 63, lq = lane & 15, g = lane >> 4;
  const int bid = blockIdx.x;
  const int xcd = bid & 7, j = bid >> 3;
  const int hb = xcd * 4 + (j & 3);
  const int qblk = j >> 2;
  const int q0 = qblk * 128 + wv * 32;

  const unsigned short* __restrict__ Q = qs + (size_t)hb * 2048 * 64;
  const unsigned short* __restrict__ K = ks + (size_t)hb * 2048 * 64;
  const unsigned short* __restrict__ V = vst + (size_t)hb * 64 * 2048;

  short8 bq[2][2];
  float cfin[2];
#pragma unroll
  for (int s = 0; s < 2; ++s) {
    const size_t qr = (size_t)(q0 + s * 16 + lq) * 64;
    bq[s][0] = *reinterpret_cast<const short8*>(Q + qr + g * 8);
    bq[s][1] = *reinterpret_cast<const short8*>(Q + qr + 32 + g * 8);
    cfin[s] = cf[hb * 2048 + q0 + s * 16 + lq];
  }

  const int srow = tid >> 3;
  const int scg = (tid & 7) ^ (srow & 7);
  const unsigned short* Ks0 = K + (size_t)srow * 64 + scg * 8;
  const unsigned short* Ks1 = K + (size_t)(srow + 32) * 64 + scg * 8;
  const unsigned short* Vs0 = V + (size_t)srow * 2048 + scg * 8;
  const unsigned short* Vs1 = V + (size_t)(srow + 32) * 2048 + scg * 8;

#define STAGE_K(bf, kt0)                                   \
  do {                                                     \
    gload16(Ks0 + (size_t)(kt0) * 64, &lk[bf][tid * 8]);   \
    gload16(Ks1 + (size_t)(kt0) * 64, &lk[bf][(tid + 256) * 8]); \
  } while (0)
#define STAGE_V(bf, kt0)                                   \
  do {                                                     \
    gload16(Vs0 + (kt0), &lv[bf][tid * 8]);                \
    gload16(Vs1 + (kt0), &lv[bf][(tid + 256) * 8]);        \
  } while (0)

  f32x4 oacc[2][4];
#pragma unroll
  for (int s = 0; s < 2; ++s)
#pragma unroll
    for (int db = 0; db < 4; ++db) oacc[s][db] = (f32x4){0.f, 0.f, 0.f, 0.f};

  float* __restrict__ atile = attns + ((size_t)hb * 2048 + q0) * 2048;
  unsigned char* __restrict__ Pw = &pscr[wv][0][0];

  // flush batch bb: 32 insts, each ONE contiguous 1 KB f32 row-run (NT)
  auto FLUSH = [&](int bb) {
    const int tb_ = lane >> 4, cc_ = (lane >> 1) & 7, hf_ = lane & 1;
#pragma unroll 8
    for (int jj = 0; jj < 32; ++jj) {
      const int ph_ = tb_ * 8 + (cc_ ^ (jj & 7));
      const uint2 w_ = *reinterpret_cast<const uint2*>(
          Pw + jj * 512 + ph_ * 16 + hf_ * 8);
      f32x4 f4_;
      f4_[0] = __uint_as_float(w_.x << 16);
      f4_[1] = __uint_as_float(w_.x & 0xffff0000u);
      f4_[2] = __uint_as_float(w_.y << 16);
      f4_[3] = __uint_as_float(w_.y & 0xffff0000u);
      float* dst_ = atile + (size_t)jj * 2048 + bb * 256 + lane * 4;
      __builtin_nontemporal_store(f4_, reinterpret_cast<f32x4*>(dst_));
    }
  };

  STAGE_K(0, 0);
  STAGE_V(0, 0);
  TILE_BARRIER(0);
  for (int t = 0; t < 32; ++t) {
    const int buf = t & 1;
    const int i = t & 3;  // batch-local tile
    if (t < 31) {
      STAGE_K(buf ^ 1, (t + 1) * 64);
      STAGE_V(buf ^ 1, (t + 1) * 64);
    }
    if (i == 0 && t > 0) FLUSH((t >> 2) - 1);  // reads P(prev batch) pre-QK ✓
    // QK^T + exp2 -> P batch buffer (chunk tb=i)
#pragma unroll
    for (int sub = 0; sub < 4; ++sub) {
      const int row = sub * 16 + lq;
      const int c0 = g ^ (row & 7);
      const unsigned short* lp = &lk[buf][row * 64];
      short8 ka0 = *reinterpret_cast<const short8*>(lp + c0 * 8);
      short8 ka1 = *reinterpret_cast<const short8*>(lp + (c0 ^ 4) * 8);
      const int off = (i * 8 + ((sub * 2 + (g >> 1)) ^ (lq & 7))) * 16 + (g & 1) * 8;
#pragma unroll
      for (int s = 0; s < 2; ++s) {
        f32x4 sa = (f32x4){0.f, 0.f, 0.f, 0.f};
        sa = MFMA16(ka0, bq[s][0], sa);
        sa = MFMA16(ka1, bq[s][1], sa);
        uint2 pr;
        pr.x = pack2bf(EXP2F(sa[0] - cfin[s]), EXP2F(sa[1] - cfin[s]));
        pr.y = pack2bf(EXP2F(sa[2] - cfin[s]), EXP2F(sa[3] - cfin[s]));
        *reinterpret_cast<uint2*>(Pw + (s * 16 + lq) * 512 + off) = pr;
      }
    }
    // PV: each V read shared by both subtiles
#pragma unroll
    for (int ch = 0; ch < 2; ++ch) {
      const int cp = (i * 8 + ((ch * 4 + g) ^ (lq & 7))) * 16;
      short8 pb0 = *reinterpret_cast<const short8*>(Pw + lq * 512 + cp);
      short8 pb1 = *reinterpret_cast<const short8*>(Pw + (16 + lq) * 512 + cp);
#pragma unroll
      for (int db = 0; db < 4; ++db) {
        const int row = db * 16 + lq;
        const int cv = (ch * 4 + g) ^ (row & 7);
        short8 va = *reinterpret_cast<const short8*>(&lv[buf][row * 64 + cv * 8]);
        oacc[0][db] = MFMA16(va, pb0, oacc[0][db]);
        oacc[1][db] = MFMA16(va, pb1, oacc[1][db]);
      }
    }
    if (t < 31) {
      if (i == 0 && t > 0) { TILE_BARRIER(32); }  // loads oldest; 32 flush stores stay
      else { TILE_BARRIER(0); }
    }
  }
  FLUSH(7);

  // epilogue: out^T tiles -> att_out[b][q][h*64+d] (bf16)
  const int h = hb >> 1, b_ = hb & 1;
#pragma unroll
  for (int s = 0; s < 2; ++s) {
    unsigned short* __restrict__ aob =
        att_out + ((size_t)(b_ * 2048 + q0 + s * 16 + lq)) * 1024 + h * 64;
#pragma unroll
    for (int db = 0; db < 4; ++db)
#pragma unroll
      for (int r = 0; r < 4; ++r)
        aob[db * 16 + g * 4 + r] = f2bf(oacc[s][db][r]);
  }
#undef STAGE_K
#undef STAGE_V
}

// ---- output projection: 64x128 tile, LDS double-buffered, bias fused ------
__global__ __launch_bounds__(256, 2) void k_oproj(
    const unsigned short* __restrict__ ao, const unsigned short* __restrict__ pw,
    const float* __restrict__ pb, float* __restrict__ out) {
  __shared__ unsigned short lA[2][4][64][8];   // 8 KB
  __shared__ unsigned short lB[2][4][128][8];  // 16 KB

  const int tid = threadIdx.x;
  const int wv = tid >> 6, lane = tid & 63, lq = lane & 15, g = lane >> 4;
  const int wr = wv >> 1, wc = wv & 1;
  const int m0 = blockIdx.x * 64;
  const int n0 = blockIdx.y * 128;

  const int rowa = tid & 63, kga = tid >> 6;
  const unsigned short* srcA = ao + (size_t)(m0 + rowa) * 1024 + kga * 8;
  unsigned short* dstA = &lA[0][0][0][0] + tid * 8;
  const int rowb = tid & 127, kgb = tid >> 7;
  const unsigned short* srcB = pw + (size_t)(n0 + rowb) * 1024 + kgb * 8;
  unsigned short* dstB = &lB[0][0][0][0] + tid * 8;

#define STAGE(bf, kc)                                       \
  do {                                                      \
    gload16(srcA + (kc), dstA + (bf)*2048);                 \
    gload16(srcB + (kc), dstB + (bf)*4096);                 \
    gload16(srcB + (kc) + 16, dstB + (bf)*4096 + 2048);     \
  } while (0)

  f32x4 acc[2][4];
#pragma unroll
  for (int i = 0; i < 2; ++i)
#pragma unroll
    for (int j = 0; j < 4; ++j) acc[i][j] = (f32x4){0.f, 0.f, 0.f, 0.f};

  STAGE(0, 0);
  __syncthreads();
  for (int t = 0; t < 32; ++t) {
    const int buf = t & 1;
    if (t < 31) STAGE(buf ^ 1, (t + 1) * 32);
    short8 a[2], b[4];
#pragma unroll
    for (int i = 0; i < 2; ++i)
      a[i] = *reinterpret_cast<const short8*>(&lA[buf][g][wr * 32 + i * 16 + lq][0]);
#pragma unroll
    for (int j = 0; j < 4; ++j)
      b[j] = *reinterpret_cast<const short8*>(&lB[buf][g][wc * 64 + j * 16 + lq][0]);
#pragma unroll
    for (int i = 0; i < 2; ++i)
#pragma unroll
      for (int j = 0; j < 4; ++j) acc[i][j] = MFMA16(a[i], b[j], acc[i][j]);
    __syncthreads();
  }
#undef STAGE

#pragma unroll
  for (int i = 0; i < 2; ++i) {
#pragma unroll
    for (int j = 0; j < 4; ++j) {
      const int n = n0 + wc * 64 + j * 16 + lq;
      const float bias = pb[n];
#pragma unroll
      for (int r = 0; r < 4; ++r) {
        const int m = m0 + wr * 32 + i * 16 + g * 4 + r;
        out[(size_t)m * 1024 + n] = acc[i][j][r] + bias;
      }
    }
  }
}

extern "C" void kernel_launch(void* const* d_in, const int* in_sizes, int n_in,
                              void* d_out, int out_size, void* d_ws, size_t ws_size,
                              hipStream_t stream) {
  const float* q = (const float*)d_in[0];
  const float* k = (const float*)d_in[1];
  const float* v = (const float*)d_in[2];
  const float* w_qs = (const float*)d_in[3];
  const float* w_ks = (const float*)d_in[4];
  const float* w_vs = (const float*)d_in[5];
  const float* proj_w = (const float*)d_in[6];
  const float* proj_b = (const float*)d_in[7];

  float* out = (float*)d_out;
  float* attns = out + (size_t)2 * 2048 * 1024;

  char* ws = (char*)d_ws;
  unsigned short* qb = (unsigned short*)(ws + ((size_t)0 << 20));
  unsigned short* kb = (unsigned short*)(ws + ((size_t)8 << 20));
  unsigned short* vb = (unsigned short*)(ws + ((size_t)16 << 20));
  unsigned short* wqt = (unsigned short*)(ws + ((size_t)24 << 20));
  unsigned short* wkt = (unsigned short*)(ws + ((size_t)26 << 20));
  unsigned short* wvt = (unsigned short*)(ws + ((size_t)28 << 20));
  unsigned short* pwb = (unsigned short*)(ws + ((size_t)30 << 20));
  unsigned short* qsb = (unsigned short*)(ws + ((size_t)32 << 20));
  unsigned short* ksb = (unsigned short*)(ws + ((size_t)40 << 20));
  unsigned short* vstb = (unsigned short*)(ws + ((size_t)48 << 20));
  unsigned short* aob = (unsigned short*)(ws + ((size_t)56 << 20));
  float* cfb = (float*)(ws + ((size_t)72 << 20));  // 32*2048 f32 = 256 KB

  k_cvt_all<<<13312, 256, 0, stream>>>(q, k, v, proj_w, qb, kb, vb, pwb);
  k_wt2<<<dim3(16, 16, 3), 256, 0, stream>>>(w_qs, w_ks, w_vs, wqt, wkt, wvt);

  k_proj<<<dim3(32, 8, 3), 256, 0, stream>>>(qb, kb, vb, wqt, wkt, wvt, qsb, ksb, vstb);
  k_attn1<<<dim3(512), 256, 0, stream>>>(qsb, ksb, cfb);
  k_attn2<<<dim3(512), 256, 0, stream>>>(qsb, ksb, vstb, cfb, attns, aob);
  k_oproj<<<dim3(64, 8), 256, 0, stream>>>(aob, pwb, proj_b, out);
}

// Round 12
// 256.653 us; speedup vs baseline: 1.2107x; 1.2107x over previous
//
#include <hip/hip_runtime.h>
#include <hip/hip_bf16.h>
#include <math.h>

// ---------------------------------------------------------------------------
// MultiheadAttention: B=2, S=2048, D_MODEL=1024, H=16, DK=DV=64
// outputs: out (B,S,1024) f32  then attns (H*B, S, S) f32, concatenated.
//
// MFMA conventions (v_mfma_f32_16x16x32_bf16):
//   A-frag: lane holds row i = lane&15, k = 8*(lane>>4)+e  (8 contiguous bf16)
//   B-frag: lane holds col j = lane&15, k = 8*(lane>>4)+e
//   C/D   : lane holds col j = lane&15, row i = 4*(lane>>4)+r   [HW-verified]
//
// R12: attn2 = R10 structure (best known: 256B NT stores, 2 blk/CU) + WAVE-
// PHASE STAGGER: waves 0-1 sweep2 passes 0..31 (cfin precomputed by k_attn1,
// which now covers only those rows); waves 2-3 run their own sweep1 during
// passes 0..31 (hidden under the store-bound phase) and sweep2 in 32..63.
// Store issue stays active the whole kernel; attn1 halves. R8-R11 data says
// attns writes cap at ~3.7 TB/s for this scatter class regardless of shape.
// ---------------------------------------------------------------------------

typedef __attribute__((ext_vector_type(8))) short short8;
typedef __attribute__((ext_vector_type(4))) float f32x4;
typedef __attribute__((ext_vector_type(4))) unsigned short ushort4v;

#define MFMA16(a, b, c) __builtin_amdgcn_mfma_f32_16x16x32_bf16(a, b, c, 0, 0, 0)
#define EXP2F(x) __builtin_amdgcn_exp2f(x)
#define LOG2F(x) __builtin_amdgcn_logf(x)

// raw barrier with counted vmem wait: N youngest vmem ops may stay outstanding
#define TILE_BARRIER(N) \
  asm volatile("s_waitcnt vmcnt(" #N ")\n\ts_barrier" ::: "memory")

static __device__ __forceinline__ unsigned short f2bf(float x) {
  unsigned int u = __float_as_uint(x);
  u += 0x7fffu + ((u >> 16) & 1u);  // RNE
  return (unsigned short)(u >> 16);
}
static __device__ __forceinline__ unsigned int pack2bf(float a, float b) {
  return (unsigned int)f2bf(a) | ((unsigned int)f2bf(b) << 16);
}

// async global->LDS, 16B per lane; LDS dest must be linear (wave base + lane*16)
static __device__ __forceinline__ void gload16(const unsigned short* g, unsigned short* l) {
  __builtin_amdgcn_global_load_lds(
      (const __attribute__((address_space(1))) unsigned int*)g,
      (__attribute__((address_space(3))) unsigned int*)l, 16, 0, 0);
}

// ---- prologue: f32->bf16 conversions + head-weight transposes, one launch -
__global__ __launch_bounds__(256) void k_pre(
    const float* __restrict__ q, const float* __restrict__ k,
    const float* __restrict__ v, const float* __restrict__ pw,
    unsigned short* __restrict__ qb, unsigned short* __restrict__ kb,
    unsigned short* __restrict__ vb, unsigned short* __restrict__ pwb,
    const float* __restrict__ s0, const float* __restrict__ s1,
    const float* __restrict__ s2, unsigned short* __restrict__ d0,
    unsigned short* __restrict__ d1, unsigned short* __restrict__ d2) {
  __shared__ float t[64][65];
  const int bid = blockIdx.x;
  const int tid = threadIdx.x;
  if (bid < 13312) {  // cvt: 3x1048576 + 262144 float4 slots, exact
    const int i = bid * 256 + tid;
    const int N1 = 1048576;
    const float* s;
    unsigned short* d;
    int off;
    if (i < N1) { s = q; d = qb; off = i; }
    else if (i < 2 * N1) { s = k; d = kb; off = i - N1; }
    else if (i < 3 * N1) { s = v; d = vb; off = i - 2 * N1; }
    else { s = pw; d = pwb; off = i - 3 * N1; }
    float4 vv = reinterpret_cast<const float4*>(s)[off];
    ushort4v o;
    o.x = f2bf(vv.x); o.y = f2bf(vv.y); o.z = f2bf(vv.z); o.w = f2bf(vv.w);
    reinterpret_cast<ushort4v*>(d)[off] = o;
    return;
  }
  // wt2: src [16][1024][64] f32 -> dst [16][64][1024] bf16; W_q scaled
  const int b2 = bid - 13312;  // 0..767
  const int z = b2 >> 8, rem = b2 & 255;
  const int h = rem >> 4, dd0 = (rem & 15) * 64;
  const float* __restrict__ s = (z == 0) ? s0 : ((z == 1) ? s1 : s2);
  unsigned short* __restrict__ d = (z == 0) ? d0 : ((z == 1) ? d1 : d2);
  const float wscale = (z == 0) ? 0.04508422002778011f : 1.0f;  // log2e/32
  const float* sp = s + ((size_t)h << 16);
  unsigned short* dp = d + ((size_t)h << 16);
#pragma unroll
  for (int it = 0; it < 16; ++it) {
    int dd = it * 4 + (tid >> 6);
    t[dd][tid & 63] = sp[(size_t)(dd0 + dd) * 64 + (tid & 63)];
  }
  __syncthreads();
#pragma unroll
  for (int it = 0; it < 16; ++it) {
    int kk = it * 4 + (tid >> 6);
    int dd = tid & 63;
    dp[(size_t)kk * 1024 + dd0 + dd] = f2bf(t[dd][kk] * wscale);
  }
}

// ---- projection GEMMs: 128x128 tile, LDS double-buffered ------------------
// qs/ks row-major [h][b][s][64], vs transposed [h][b][64][s]
__global__ __launch_bounds__(256, 3) void k_proj(
    const unsigned short* __restrict__ qb, const unsigned short* __restrict__ kb,
    const unsigned short* __restrict__ vb,
    const unsigned short* __restrict__ wqt, const unsigned short* __restrict__ wkt,
    const unsigned short* __restrict__ wvt,
    unsigned short* __restrict__ qs, unsigned short* __restrict__ ks,
    unsigned short* __restrict__ vst) {
  __shared__ unsigned short lA[2][4][128][8];  // 16 KB
  __shared__ unsigned short lB[2][4][128][8];  // 16 KB

  const int mode = blockIdx.z;
  const unsigned short* __restrict__ A = (mode == 0) ? qb : ((mode == 1) ? kb : vb);
  const unsigned short* __restrict__ W = (mode == 0) ? wqt : ((mode == 1) ? wkt : wvt);

  const int tid = threadIdx.x;
  const int wv = tid >> 6, lane = tid & 63, lq = lane & 15, g = lane >> 4;
  const int wr = wv >> 1, wc = wv & 1;
  const int m0 = blockIdx.x * 128;
  const int n0 = blockIdx.y * 128;

  const int rowm = tid & 127, kg = tid >> 7;
  const unsigned short* srcA = A + (size_t)(m0 + rowm) * 1024 + kg * 8;
  const unsigned short* srcB = W + (size_t)(n0 + rowm) * 1024 + kg * 8;
  unsigned short* dstA = &lA[0][0][0][0] + tid * 8;
  unsigned short* dstB = &lB[0][0][0][0] + tid * 8;

#define STAGE(bf, kc)                                       \
  do {                                                      \
    gload16(srcA + (kc), dstA + (bf)*4096);                 \
    gload16(srcA + (kc) + 16, dstA + (bf)*4096 + 2048);     \
    gload16(srcB + (kc), dstB + (bf)*4096);                 \
    gload16(srcB + (kc) + 16, dstB + (bf)*4096 + 2048);     \
  } while (0)

  f32x4 acc[4][4];
#pragma unroll
  for (int i = 0; i < 4; ++i)
#pragma unroll
    for (int j = 0; j < 4; ++j) acc[i][j] = (f32x4){0.f, 0.f, 0.f, 0.f};

  STAGE(0, 0);
  __syncthreads();
  for (int t = 0; t < 32; ++t) {
    const int buf = t & 1;
    if (t < 31) STAGE(buf ^ 1, (t + 1) * 32);
    short8 a[4], b[4];
#pragma unroll
    for (int i = 0; i < 4; ++i)
      a[i] = *reinterpret_cast<const short8*>(&lA[buf][g][wr * 64 + i * 16 + lq][0]);
#pragma unroll
    for (int j = 0; j < 4; ++j)
      b[j] = *reinterpret_cast<const short8*>(&lB[buf][g][wc * 64 + j * 16 + lq][0]);
#pragma unroll
    for (int i = 0; i < 4; ++i)
#pragma unroll
      for (int j = 0; j < 4; ++j) acc[i][j] = MFMA16(a[i], b[j], acc[i][j]);
    __syncthreads();
  }
#undef STAGE

#pragma unroll
  for (int i = 0; i < 4; ++i) {
#pragma unroll
    for (int j = 0; j < 4; ++j) {
      const int n = n0 + wc * 64 + j * 16 + lq;
      const int h = n >> 6, dk = n & 63;
#pragma unroll
      for (int r = 0; r < 4; ++r) {
        const int m = m0 + wr * 64 + i * 16 + g * 4 + r;
        const int b_ = m >> 11, sq = m & 2047;
        const unsigned short val = f2bf(acc[i][j][r]);
        if (mode == 0)
          qs[(((size_t)h * 2 + b_) * 2048 + sq) * 64 + dk] = val;
        else if (mode == 1)
          ks[(((size_t)h * 2 + b_) * 2048 + sq) * 64 + dk] = val;
        else
          vst[(((size_t)h * 2 + b_) * 64 + dk) * 2048 + sq] = val;
      }
    }
  }
}

// ---- attention sweep 1 (HALF rows: first 64 of each 128-row block) --------
// grid 256: xcd=bid&7, m=bid>>3; waves 0-1 -> qpair 2*qi, waves 2-3 -> 2*qi+1
__global__ __launch_bounds__(256, 2) void k_attn1(
    const unsigned short* __restrict__ qs, const unsigned short* __restrict__ ks,
    float* __restrict__ cf) {
  __shared__ unsigned short lk[2][4096];

  const int tid = threadIdx.x;
  const int wv = tid >> 6, lane = tid & 63, lq = lane & 15, g = lane >> 4;
  const int bid = blockIdx.x;
  const int xcd = bid & 7, m = bid >> 3;     // m 0..31
  const int hb = xcd * 4 + (m & 3);
  const int qi = m >> 2;                     // 0..7
  const int qpair = 2 * qi + (wv >> 1);      // 0..15
  const int q0 = qpair * 128 + (wv & 1) * 32;  // A-half rows [qpair*128, +64)

  const unsigned short* __restrict__ Q = qs + (size_t)hb * 2048 * 64;
  const unsigned short* __restrict__ K = ks + (size_t)hb * 2048 * 64;

  short8 bq[2][2];
#pragma unroll
  for (int s = 0; s < 2; ++s) {
    const size_t qr = (size_t)(q0 + s * 16 + lq) * 64;
    bq[s][0] = *reinterpret_cast<const short8*>(Q + qr + g * 8);
    bq[s][1] = *reinterpret_cast<const short8*>(Q + qr + 32 + g * 8);
  }

  const int srow = tid >> 3;
  const int scg = (tid & 7) ^ (srow & 7);
  const unsigned short* Ks0 = K + (size_t)srow * 64 + scg * 8;
  const unsigned short* Ks1 = K + (size_t)(srow + 32) * 64 + scg * 8;

#define STAGE_K(bf, kt0)                                   \
  do {                                                     \
    gload16(Ks0 + (size_t)(kt0) * 64, &lk[bf][tid * 8]);   \
    gload16(Ks1 + (size_t)(kt0) * 64, &lk[bf][(tid + 256) * 8]); \
  } while (0)

  float lrun[2] = {0.f, 0.f};
  STAGE_K(0, 0);
  TILE_BARRIER(0);
  for (int t = 0; t < 32; ++t) {
    const int buf = t & 1;
    if (t < 31) STAGE_K(buf ^ 1, (t + 1) * 64);
#pragma unroll
    for (int sub = 0; sub < 4; ++sub) {
      const int row = sub * 16 + lq;
      const int c0 = g ^ (row & 7);
      const unsigned short* lp = &lk[buf][row * 64];
      short8 ka0 = *reinterpret_cast<const short8*>(lp + c0 * 8);
      short8 ka1 = *reinterpret_cast<const short8*>(lp + (c0 ^ 4) * 8);
#pragma unroll
      for (int s = 0; s < 2; ++s) {
        f32x4 sa = (f32x4){0.f, 0.f, 0.f, 0.f};
        sa = MFMA16(ka0, bq[s][0], sa);
        sa = MFMA16(ka1, bq[s][1], sa);  // log2 units (W_q pre-scaled)
        lrun[s] += (EXP2F(sa[0]) + EXP2F(sa[1])) + (EXP2F(sa[2]) + EXP2F(sa[3]));
      }
    }
    TILE_BARRIER(0);
  }
#pragma unroll
  for (int s = 0; s < 2; ++s) {
    float lc = lrun[s] + __shfl_xor(lrun[s], 16);
    lc += __shfl_xor(lc, 32);
    if (g == 0) cf[hb * 2048 + q0 + s * 16 + lq] = LOG2F(lc);
  }
#undef STAGE_K
}

// ---- attention sweep 2: wave-phase staggered ------------------------------
// waves 0-1 (rows +0..63): sweep2 in passes 0..31 (cfin from cf[]).
// waves 2-3 (rows +64..127): sweep1 in passes 0..31, sweep2 in passes 32..63.
__global__ __launch_bounds__(256, 2) void k_attn2(
    const unsigned short* __restrict__ qs, const unsigned short* __restrict__ ks,
    const unsigned short* __restrict__ vst, const float* __restrict__ cf,
    float* __restrict__ attns, unsigned short* __restrict__ att_out) {
  __shared__ unsigned short lk[2][4096];       // K tile, 16 KB
  __shared__ unsigned short lv[2][4096];       // V^T tile, 16 KB
  __shared__ unsigned char pscr[4][2][2048];   // per-wave per-subtile P, 16 KB

  const int tid = threadIdx.x;
  const int wv = tid >> 6, lane = tid & 63, lq = lane & 15, g = lane >> 4;
  const int bid = blockIdx.x;
  const int xcd = bid & 7, j = bid >> 3;
  const int hb = xcd * 4 + (j & 3);
  const int qblk = j >> 2;               // 0..15
  const int q0 = qblk * 128 + wv * 32;
  const bool isA = (wv < 2);

  const unsigned short* __restrict__ Q = qs + (size_t)hb * 2048 * 64;
  const unsigned short* __restrict__ K = ks + (size_t)hb * 2048 * 64;
  const unsigned short* __restrict__ V = vst + (size_t)hb * 64 * 2048;

  short8 bq[2][2];
  float cfin[2] = {0.f, 0.f};
#pragma unroll
  for (int s = 0; s < 2; ++s) {
    const size_t qr = (size_t)(q0 + s * 16 + lq) * 64;
    bq[s][0] = *reinterpret_cast<const short8*>(Q + qr + g * 8);
    bq[s][1] = *reinterpret_cast<const short8*>(Q + qr + 32 + g * 8);
  }
  if (isA) {
#pragma unroll
    for (int s = 0; s < 2; ++s) cfin[s] = cf[hb * 2048 + q0 + s * 16 + lq];
  }

  const int srow = tid >> 3;
  const int scg = (tid & 7) ^ (srow & 7);
  const unsigned short* Ks0 = K + (size_t)srow * 64 + scg * 8;
  const unsigned short* Ks1 = K + (size_t)(srow + 32) * 64 + scg * 8;
  const unsigned short* Vs0 = V + (size_t)srow * 2048 + scg * 8;
  const unsigned short* Vs1 = V + (size_t)(srow + 32) * 2048 + scg * 8;

#define STAGE_K(bf, kt0)                                   \
  do {                                                     \
    gload16(Ks0 + (size_t)(kt0) * 64, &lk[bf][tid * 8]);   \
    gload16(Ks1 + (size_t)(kt0) * 64, &lk[bf][(tid + 256) * 8]); \
  } while (0)
#define STAGE_V(bf, kt0)                                   \
  do {                                                     \
    gload16(Vs0 + (kt0), &lv[bf][tid * 8]);                \
    gload16(Vs1 + (kt0), &lv[bf][(tid + 256) * 8]);        \
  } while (0)

  f32x4 oacc[2][4];
#pragma unroll
  for (int s = 0; s < 2; ++s)
#pragma unroll
    for (int db = 0; db < 4; ++db) oacc[s][db] = (f32x4){0.f, 0.f, 0.f, 0.f};
  float lrun[2] = {0.f, 0.f};

  float* __restrict__ atile = attns + ((size_t)hb * 2048 + q0) * 2048;
  unsigned char* __restrict__ P0 = &pscr[wv][0][0];
  unsigned char* __restrict__ P1 = &pscr[wv][1][0];

  STAGE_K(0, 0);
  STAGE_V(0, 0);
  TILE_BARRIER(0);
  for (int p = 0; p < 64; ++p) {
    const int tl = p & 31;
    const int buf = p & 1;
    if (p < 63) {
      const int nt_ = ((p + 1) & 31) * 64;
      STAGE_K(buf ^ 1, nt_);
      STAGE_V(buf ^ 1, nt_);
    }
    const bool s2 = (isA == (p < 32));  // this wave runs sweep2 this pass
    if (s2) {
      // QK^T + exp2 -> P scratch
#pragma unroll
      for (int sub = 0; sub < 4; ++sub) {
        const int row = sub * 16 + lq;
        const int c0 = g ^ (row & 7);
        const unsigned short* lp = &lk[buf][row * 64];
        short8 ka0 = *reinterpret_cast<const short8*>(lp + c0 * 8);
        short8 ka1 = *reinterpret_cast<const short8*>(lp + (c0 ^ 4) * 8);
        const int cw = ((sub * 2 + (g >> 1)) ^ (lq & 7)) * 16 + (g & 1) * 8;
#pragma unroll
        for (int s = 0; s < 2; ++s) {
          f32x4 sa = (f32x4){0.f, 0.f, 0.f, 0.f};
          sa = MFMA16(ka0, bq[s][0], sa);
          sa = MFMA16(ka1, bq[s][1], sa);
          uint2 pr;
          pr.x = pack2bf(EXP2F(sa[0] - cfin[s]), EXP2F(sa[1] - cfin[s]));
          pr.y = pack2bf(EXP2F(sa[2] - cfin[s]), EXP2F(sa[3] - cfin[s]));
          *reinterpret_cast<uint2*>((s ? P1 : P0) + lq * 128 + cw) = pr;
        }
      }
      // attns NT stores: 4 rows x 256 B per instruction
#pragma unroll
      for (int s = 0; s < 2; ++s) {
        const unsigned char* Ps = s ? P1 : P0;
#pragma unroll
        for (int st = 0; st < 4; ++st) {
          const int rr = st * 4 + g;
          const int cr = ((lq >> 1) ^ (rr & 7)) * 16 + (lq & 1) * 8;
          const uint2 w = *reinterpret_cast<const uint2*>(Ps + rr * 128 + cr);
          f32x4 f4;
          f4[0] = __uint_as_float(w.x << 16);
          f4[1] = __uint_as_float(w.x & 0xffff0000u);
          f4[2] = __uint_as_float(w.y << 16);
          f4[3] = __uint_as_float(w.y & 0xffff0000u);
          float* dst = atile + (size_t)(s * 16 + rr) * 2048 + tl * 64 + lq * 4;
          __builtin_nontemporal_store(f4, reinterpret_cast<f32x4*>(dst));
        }
      }
      // PV
#pragma unroll
      for (int ch = 0; ch < 2; ++ch) {
        const int cp = ((ch * 4 + g) ^ (lq & 7)) * 16;
        short8 pb0 = *reinterpret_cast<const short8*>(P0 + lq * 128 + cp);
        short8 pb1 = *reinterpret_cast<const short8*>(P1 + lq * 128 + cp);
#pragma unroll
        for (int db = 0; db < 4; ++db) {
          const int row = db * 16 + lq;
          const int cv = (ch * 4 + g) ^ (row & 7);
          short8 va = *reinterpret_cast<const short8*>(&lv[buf][row * 64 + cv * 8]);
          oacc[0][db] = MFMA16(va, pb0, oacc[0][db]);
          oacc[1][db] = MFMA16(va, pb1, oacc[1][db]);
        }
      }
    } else if (!isA) {
      // B-wave sweep1 (passes 0..31): denominator accumulation, no stores
#pragma unroll
      for (int sub = 0; sub < 4; ++sub) {
        const int row = sub * 16 + lq;
        const int c0 = g ^ (row & 7);
        const unsigned short* lp = &lk[buf][row * 64];
        short8 ka0 = *reinterpret_cast<const short8*>(lp + c0 * 8);
        short8 ka1 = *reinterpret_cast<const short8*>(lp + (c0 ^ 4) * 8);
#pragma unroll
        for (int s = 0; s < 2; ++s) {
          f32x4 sa = (f32x4){0.f, 0.f, 0.f, 0.f};
          sa = MFMA16(ka0, bq[s][0], sa);
          sa = MFMA16(ka1, bq[s][1], sa);
          lrun[s] += (EXP2F(sa[0]) + EXP2F(sa[1])) + (EXP2F(sa[2]) + EXP2F(sa[3]));
        }
      }
      if (p == 31) {
#pragma unroll
        for (int s = 0; s < 2; ++s) {
          float lc = lrun[s] + __shfl_xor(lrun[s], 16);
          lc += __shfl_xor(lc, 32);
          cfin[s] = LOG2F(lc);
        }
      }
    }
    if (p < 63) {
      if (s2) { TILE_BARRIER(8); }   // store-active: leave own 8 NT stores flying
      else    { TILE_BARRIER(0); }   // no stores: must drain own staged loads
    }
  }

  // epilogue: out^T tiles -> att_out[b][q][h*64+d] (bf16)
  const int h = hb >> 1, b_ = hb & 1;
#pragma unroll
  for (int s = 0; s < 2; ++s) {
    unsigned short* __restrict__ aob =
        att_out + ((size_t)(b_ * 2048 + q0 + s * 16 + lq)) * 1024 + h * 64;
#pragma unroll
    for (int db = 0; db < 4; ++db)
#pragma unroll
      for (int r = 0; r < 4; ++r)
        aob[db * 16 + g * 4 + r] = f2bf(oacc[s][db][r]);
  }
#undef STAGE_K
#undef STAGE_V
}

// ---- output projection: 64x128 tile, LDS double-buffered, bias fused ------
__global__ __launch_bounds__(256, 2) void k_oproj(
    const unsigned short* __restrict__ ao, const unsigned short* __restrict__ pw,
    const float* __restrict__ pb, float* __restrict__ out) {
  __shared__ unsigned short lA[2][4][64][8];   // 8 KB
  __shared__ unsigned short lB[2][4][128][8];  // 16 KB

  const int tid = threadIdx.x;
  const int wv = tid >> 6, lane = tid & 63, lq = lane & 15, g = lane >> 4;
  const int wr = wv >> 1, wc = wv & 1;
  const int m0 = blockIdx.x * 64;
  const int n0 = blockIdx.y * 128;

  const int rowa = tid & 63, kga = tid >> 6;
  const unsigned short* srcA = ao + (size_t)(m0 + rowa) * 1024 + kga * 8;
  unsigned short* dstA = &lA[0][0][0][0] + tid * 8;
  const int rowb = tid & 127, kgb = tid >> 7;
  const unsigned short* srcB = pw + (size_t)(n0 + rowb) * 1024 + kgb * 8;
  unsigned short* dstB = &lB[0][0][0][0] + tid * 8;

#define STAGE(bf, kc)                                       \
  do {                                                      \
    gload16(srcA + (kc), dstA + (bf)*2048);                 \
    gload16(srcB + (kc), dstB + (bf)*4096);                 \
    gload16(srcB + (kc) + 16, dstB + (bf)*4096 + 2048);     \
  } while (0)

  f32x4 acc[2][4];
#pragma unroll
  for (int i = 0; i < 2; ++i)
#pragma unroll
    for (int j = 0; j < 4; ++j) acc[i][j] = (f32x4){0.f, 0.f, 0.f, 0.f};

  STAGE(0, 0);
  __syncthreads();
  for (int t = 0; t < 32; ++t) {
    const int buf = t & 1;
    if (t < 31) STAGE(buf ^ 1, (t + 1) * 32);
    short8 a[2], b[4];
#pragma unroll
    for (int i = 0; i < 2; ++i)
      a[i] = *reinterpret_cast<const short8*>(&lA[buf][g][wr * 32 + i * 16 + lq][0]);
#pragma unroll
    for (int j = 0; j < 4; ++j)
      b[j] = *reinterpret_cast<const short8*>(&lB[buf][g][wc * 64 + j * 16 + lq][0]);
#pragma unroll
    for (int i = 0; i < 2; ++i)
#pragma unroll
      for (int j = 0; j < 4; ++j) acc[i][j] = MFMA16(a[i], b[j], acc[i][j]);
    __syncthreads();
  }
#undef STAGE

#pragma unroll
  for (int i = 0; i < 2; ++i) {
#pragma unroll
    for (int j = 0; j < 4; ++j) {
      const int n = n0 + wc * 64 + j * 16 + lq;
      const float bias = pb[n];
#pragma unroll
      for (int r = 0; r < 4; ++r) {
        const int m = m0 + wr * 32 + i * 16 + g * 4 + r;
        out[(size_t)m * 1024 + n] = acc[i][j][r] + bias;
      }
    }
  }
}

extern "C" void kernel_launch(void* const* d_in, const int* in_sizes, int n_in,
                              void* d_out, int out_size, void* d_ws, size_t ws_size,
                              hipStream_t stream) {
  const float* q = (const float*)d_in[0];
  const float* k = (const float*)d_in[1];
  const float* v = (const float*)d_in[2];
  const float* w_qs = (const float*)d_in[3];
  const float* w_ks = (const float*)d_in[4];
  const float* w_vs = (const float*)d_in[5];
  const float* proj_w = (const float*)d_in[6];
  const float* proj_b = (const float*)d_in[7];

  float* out = (float*)d_out;
  float* attns = out + (size_t)2 * 2048 * 1024;

  char* ws = (char*)d_ws;
  unsigned short* qb = (unsigned short*)(ws + ((size_t)0 << 20));
  unsigned short* kb = (unsigned short*)(ws + ((size_t)8 << 20));
  unsigned short* vb = (unsigned short*)(ws + ((size_t)16 << 20));
  unsigned short* wqt = (unsigned short*)(ws + ((size_t)24 << 20));
  unsigned short* wkt = (unsigned short*)(ws + ((size_t)26 << 20));
  unsigned short* wvt = (unsigned short*)(ws + ((size_t)28 << 20));
  unsigned short* pwb = (unsigned short*)(ws + ((size_t)30 << 20));
  unsigned short* qsb = (unsigned short*)(ws + ((size_t)32 << 20));
  unsigned short* ksb = (unsigned short*)(ws + ((size_t)40 << 20));
  unsigned short* vstb = (unsigned short*)(ws + ((size_t)48 << 20));
  unsigned short* aob = (unsigned short*)(ws + ((size_t)56 << 20));
  float* cfb = (float*)(ws + ((size_t)72 << 20));  // 32*2048 f32 = 256 KB

  k_pre<<<14080, 256, 0, stream>>>(q, k, v, proj_w, qb, kb, vb, pwb,
                                   w_qs, w_ks, w_vs, wqt, wkt, wvt);
  k_proj<<<dim3(32, 8, 3), 256, 0, stream>>>(qb, kb, vb, wqt, wkt, wvt, qsb, ksb, vstb);
  k_attn1<<<dim3(256), 256, 0, stream>>>(qsb, ksb, cfb);
  k_attn2<<<dim3(512), 256, 0, stream>>>(qsb, ksb, vstb, cfb, attns, aob);
  k_oproj<<<dim3(64, 8), 256, 0, stream>>>(aob, pwb, proj_b, out);
}

// Round 13
// 249.591 us; speedup vs baseline: 1.2449x; 1.0283x over previous
//
#include <hip/hip_runtime.h>
#include <hip/hip_bf16.h>
#include <math.h>

// ---------------------------------------------------------------------------
// MultiheadAttention: B=2, S=2048, D_MODEL=1024, H=16, DK=DV=64
// outputs: out (B,S,1024) f32  then attns (H*B, S, S) f32, concatenated.
//
// MFMA conventions (v_mfma_f32_16x16x32_bf16):
//   A-frag: lane holds row i = lane&15, k = 8*(lane>>4)+e  (8 contiguous bf16)
//   B-frag: lane holds col j = lane&15, k = 8*(lane>>4)+e
//   C/D   : lane holds col j = lane&15, row i = 4*(lane>>4)+r   [HW-verified]
//
// R13: attn2 = R12 (wave-phase stagger) + W=2 TILE BATCHING: P for two
// consecutive K-tiles accumulates in pscr (32 KB), flushed every 2nd pass
// as 512B-contiguous runs (2 rows x 512B per store inst). LDS 64 KB keeps
// 2 blk/CU. Clean test of run-length 256B->512B at fixed occupancy.
// ---------------------------------------------------------------------------

typedef __attribute__((ext_vector_type(8))) short short8;
typedef __attribute__((ext_vector_type(4))) float f32x4;
typedef __attribute__((ext_vector_type(4))) unsigned short ushort4v;

#define MFMA16(a, b, c) __builtin_amdgcn_mfma_f32_16x16x32_bf16(a, b, c, 0, 0, 0)
#define EXP2F(x) __builtin_amdgcn_exp2f(x)
#define LOG2F(x) __builtin_amdgcn_logf(x)

// raw barrier with counted vmem wait: N youngest vmem ops may stay outstanding
#define TILE_BARRIER(N) \
  asm volatile("s_waitcnt vmcnt(" #N ")\n\ts_barrier" ::: "memory")

static __device__ __forceinline__ unsigned short f2bf(float x) {
  unsigned int u = __float_as_uint(x);
  u += 0x7fffu + ((u >> 16) & 1u);  // RNE
  return (unsigned short)(u >> 16);
}
static __device__ __forceinline__ unsigned int pack2bf(float a, float b) {
  return (unsigned int)f2bf(a) | ((unsigned int)f2bf(b) << 16);
}

// async global->LDS, 16B per lane; LDS dest must be linear (wave base + lane*16)
static __device__ __forceinline__ void gload16(const unsigned short* g, unsigned short* l) {
  __builtin_amdgcn_global_load_lds(
      (const __attribute__((address_space(1))) unsigned int*)g,
      (__attribute__((address_space(3))) unsigned int*)l, 16, 0, 0);
}

// ---- prologue: f32->bf16 conversions + head-weight transposes, one launch -
__global__ __launch_bounds__(256) void k_pre(
    const float* __restrict__ q, const float* __restrict__ k,
    const float* __restrict__ v, const float* __restrict__ pw,
    unsigned short* __restrict__ qb, unsigned short* __restrict__ kb,
    unsigned short* __restrict__ vb, unsigned short* __restrict__ pwb,
    const float* __restrict__ s0, const float* __restrict__ s1,
    const float* __restrict__ s2, unsigned short* __restrict__ d0,
    unsigned short* __restrict__ d1, unsigned short* __restrict__ d2) {
  __shared__ float t[64][65];
  const int bid = blockIdx.x;
  const int tid = threadIdx.x;
  if (bid < 13312) {  // cvt: 3x1048576 + 262144 float4 slots, exact
    const int i = bid * 256 + tid;
    const int N1 = 1048576;
    const float* s;
    unsigned short* d;
    int off;
    if (i < N1) { s = q; d = qb; off = i; }
    else if (i < 2 * N1) { s = k; d = kb; off = i - N1; }
    else if (i < 3 * N1) { s = v; d = vb; off = i - 2 * N1; }
    else { s = pw; d = pwb; off = i - 3 * N1; }
    float4 vv = reinterpret_cast<const float4*>(s)[off];
    ushort4v o;
    o.x = f2bf(vv.x); o.y = f2bf(vv.y); o.z = f2bf(vv.z); o.w = f2bf(vv.w);
    reinterpret_cast<ushort4v*>(d)[off] = o;
    return;
  }
  // wt2: src [16][1024][64] f32 -> dst [16][64][1024] bf16; W_q scaled
  const int b2 = bid - 13312;  // 0..767
  const int z = b2 >> 8, rem = b2 & 255;
  const int h = rem >> 4, dd0 = (rem & 15) * 64;
  const float* __restrict__ s = (z == 0) ? s0 : ((z == 1) ? s1 : s2);
  unsigned short* __restrict__ d = (z == 0) ? d0 : ((z == 1) ? d1 : d2);
  const float wscale = (z == 0) ? 0.04508422002778011f : 1.0f;  // log2e/32
  const float* sp = s + ((size_t)h << 16);
  unsigned short* dp = d + ((size_t)h << 16);
#pragma unroll
  for (int it = 0; it < 16; ++it) {
    int dd = it * 4 + (tid >> 6);
    t[dd][tid & 63] = sp[(size_t)(dd0 + dd) * 64 + (tid & 63)];
  }
  __syncthreads();
#pragma unroll
  for (int it = 0; it < 16; ++it) {
    int kk = it * 4 + (tid >> 6);
    int dd = tid & 63;
    dp[(size_t)kk * 1024 + dd0 + dd] = f2bf(t[dd][kk] * wscale);
  }
}

// ---- projection GEMMs: 128x128 tile, LDS double-buffered ------------------
// qs/ks row-major [h][b][s][64], vs transposed [h][b][64][s]
__global__ __launch_bounds__(256, 3) void k_proj(
    const unsigned short* __restrict__ qb, const unsigned short* __restrict__ kb,
    const unsigned short* __restrict__ vb,
    const unsigned short* __restrict__ wqt, const unsigned short* __restrict__ wkt,
    const unsigned short* __restrict__ wvt,
    unsigned short* __restrict__ qs, unsigned short* __restrict__ ks,
    unsigned short* __restrict__ vst) {
  __shared__ unsigned short lA[2][4][128][8];  // 16 KB
  __shared__ unsigned short lB[2][4][128][8];  // 16 KB

  const int mode = blockIdx.z;
  const unsigned short* __restrict__ A = (mode == 0) ? qb : ((mode == 1) ? kb : vb);
  const unsigned short* __restrict__ W = (mode == 0) ? wqt : ((mode == 1) ? wkt : wvt);

  const int tid = threadIdx.x;
  const int wv = tid >> 6, lane = tid & 63, lq = lane & 15, g = lane >> 4;
  const int wr = wv >> 1, wc = wv & 1;
  const int m0 = blockIdx.x * 128;
  const int n0 = blockIdx.y * 128;

  const int rowm = tid & 127, kg = tid >> 7;
  const unsigned short* srcA = A + (size_t)(m0 + rowm) * 1024 + kg * 8;
  const unsigned short* srcB = W + (size_t)(n0 + rowm) * 1024 + kg * 8;
  unsigned short* dstA = &lA[0][0][0][0] + tid * 8;
  unsigned short* dstB = &lB[0][0][0][0] + tid * 8;

#define STAGE(bf, kc)                                       \
  do {                                                      \
    gload16(srcA + (kc), dstA + (bf)*4096);                 \
    gload16(srcA + (kc) + 16, dstA + (bf)*4096 + 2048);     \
    gload16(srcB + (kc), dstB + (bf)*4096);                 \
    gload16(srcB + (kc) + 16, dstB + (bf)*4096 + 2048);     \
  } while (0)

  f32x4 acc[4][4];
#pragma unroll
  for (int i = 0; i < 4; ++i)
#pragma unroll
    for (int j = 0; j < 4; ++j) acc[i][j] = (f32x4){0.f, 0.f, 0.f, 0.f};

  STAGE(0, 0);
  __syncthreads();
  for (int t = 0; t < 32; ++t) {
    const int buf = t & 1;
    if (t < 31) STAGE(buf ^ 1, (t + 1) * 32);
    short8 a[4], b[4];
#pragma unroll
    for (int i = 0; i < 4; ++i)
      a[i] = *reinterpret_cast<const short8*>(&lA[buf][g][wr * 64 + i * 16 + lq][0]);
#pragma unroll
    for (int j = 0; j < 4; ++j)
      b[j] = *reinterpret_cast<const short8*>(&lB[buf][g][wc * 64 + j * 16 + lq][0]);
#pragma unroll
    for (int i = 0; i < 4; ++i)
#pragma unroll
      for (int j = 0; j < 4; ++j) acc[i][j] = MFMA16(a[i], b[j], acc[i][j]);
    __syncthreads();
  }
#undef STAGE

#pragma unroll
  for (int i = 0; i < 4; ++i) {
#pragma unroll
    for (int j = 0; j < 4; ++j) {
      const int n = n0 + wc * 64 + j * 16 + lq;
      const int h = n >> 6, dk = n & 63;
#pragma unroll
      for (int r = 0; r < 4; ++r) {
        const int m = m0 + wr * 64 + i * 16 + g * 4 + r;
        const int b_ = m >> 11, sq = m & 2047;
        const unsigned short val = f2bf(acc[i][j][r]);
        if (mode == 0)
          qs[(((size_t)h * 2 + b_) * 2048 + sq) * 64 + dk] = val;
        else if (mode == 1)
          ks[(((size_t)h * 2 + b_) * 2048 + sq) * 64 + dk] = val;
        else
          vst[(((size_t)h * 2 + b_) * 64 + dk) * 2048 + sq] = val;
      }
    }
  }
}

// ---- attention sweep 1 (HALF rows: first 64 of each 128-row block) --------
__global__ __launch_bounds__(256, 2) void k_attn1(
    const unsigned short* __restrict__ qs, const unsigned short* __restrict__ ks,
    float* __restrict__ cf) {
  __shared__ unsigned short lk[2][4096];

  const int tid = threadIdx.x;
  const int wv = tid >> 6, lane = tid & 63, lq = lane & 15, g = lane >> 4;
  const int bid = blockIdx.x;
  const int xcd = bid & 7, m = bid >> 3;     // m 0..31
  const int hb = xcd * 4 + (m & 3);
  const int qi = m >> 2;                     // 0..7
  const int qpair = 2 * qi + (wv >> 1);      // 0..15
  const int q0 = qpair * 128 + (wv & 1) * 32;  // A-half rows [qpair*128, +64)

  const unsigned short* __restrict__ Q = qs + (size_t)hb * 2048 * 64;
  const unsigned short* __restrict__ K = ks + (size_t)hb * 2048 * 64;

  short8 bq[2][2];
#pragma unroll
  for (int s = 0; s < 2; ++s) {
    const size_t qr = (size_t)(q0 + s * 16 + lq) * 64;
    bq[s][0] = *reinterpret_cast<const short8*>(Q + qr + g * 8);
    bq[s][1] = *reinterpret_cast<const short8*>(Q + qr + 32 + g * 8);
  }

  const int srow = tid >> 3;
  const int scg = (tid & 7) ^ (srow & 7);
  const unsigned short* Ks0 = K + (size_t)srow * 64 + scg * 8;
  const unsigned short* Ks1 = K + (size_t)(srow + 32) * 64 + scg * 8;

#define STAGE_K(bf, kt0)                                   \
  do {                                                     \
    gload16(Ks0 + (size_t)(kt0) * 64, &lk[bf][tid * 8]);   \
    gload16(Ks1 + (size_t)(kt0) * 64, &lk[bf][(tid + 256) * 8]); \
  } while (0)

  float lrun[2] = {0.f, 0.f};
  STAGE_K(0, 0);
  TILE_BARRIER(0);
  for (int t = 0; t < 32; ++t) {
    const int buf = t & 1;
    if (t < 31) STAGE_K(buf ^ 1, (t + 1) * 64);
#pragma unroll
    for (int sub = 0; sub < 4; ++sub) {
      const int row = sub * 16 + lq;
      const int c0 = g ^ (row & 7);
      const unsigned short* lp = &lk[buf][row * 64];
      short8 ka0 = *reinterpret_cast<const short8*>(lp + c0 * 8);
      short8 ka1 = *reinterpret_cast<const short8*>(lp + (c0 ^ 4) * 8);
#pragma unroll
      for (int s = 0; s < 2; ++s) {
        f32x4 sa = (f32x4){0.f, 0.f, 0.f, 0.f};
        sa = MFMA16(ka0, bq[s][0], sa);
        sa = MFMA16(ka1, bq[s][1], sa);  // log2 units (W_q pre-scaled)
        lrun[s] += (EXP2F(sa[0]) + EXP2F(sa[1])) + (EXP2F(sa[2]) + EXP2F(sa[3]));
      }
    }
    TILE_BARRIER(0);
  }
#pragma unroll
  for (int s = 0; s < 2; ++s) {
    float lc = lrun[s] + __shfl_xor(lrun[s], 16);
    lc += __shfl_xor(lc, 32);
    if (g == 0) cf[hb * 2048 + q0 + s * 16 + lq] = LOG2F(lc);
  }
#undef STAGE_K
}

// ---- attention sweep 2: staggered + W=2 batched 512B-run NT stores --------
__global__ __launch_bounds__(256, 2) void k_attn2(
    const unsigned short* __restrict__ qs, const unsigned short* __restrict__ ks,
    const unsigned short* __restrict__ vst, const float* __restrict__ cf,
    float* __restrict__ attns, unsigned short* __restrict__ att_out) {
  __shared__ unsigned short lk[2][4096];       // K tile, 16 KB
  __shared__ unsigned short lv[2][4096];       // V^T tile, 16 KB
  __shared__ unsigned char pscr[4][8192];      // per-wave P: [tile2|s][16r][128B], 32 KB

  const int tid = threadIdx.x;
  const int wv = tid >> 6, lane = tid & 63, lq = lane & 15, g = lane >> 4;
  const int bid = blockIdx.x;
  const int xcd = bid & 7, j = bid >> 3;
  const int hb = xcd * 4 + (j & 3);
  const int qblk = j >> 2;               // 0..15
  const int q0 = qblk * 128 + wv * 32;
  const bool isA = (wv < 2);

  const unsigned short* __restrict__ Q = qs + (size_t)hb * 2048 * 64;
  const unsigned short* __restrict__ K = ks + (size_t)hb * 2048 * 64;
  const unsigned short* __restrict__ V = vst + (size_t)hb * 64 * 2048;

  short8 bq[2][2];
  float cfin[2] = {0.f, 0.f};
#pragma unroll
  for (int s = 0; s < 2; ++s) {
    const size_t qr = (size_t)(q0 + s * 16 + lq) * 64;
    bq[s][0] = *reinterpret_cast<const short8*>(Q + qr + g * 8);
    bq[s][1] = *reinterpret_cast<const short8*>(Q + qr + 32 + g * 8);
  }
  if (isA) {
#pragma unroll
    for (int s = 0; s < 2; ++s) cfin[s] = cf[hb * 2048 + q0 + s * 16 + lq];
  }

  const int srow = tid >> 3;
  const int scg = (tid & 7) ^ (srow & 7);
  const unsigned short* Ks0 = K + (size_t)srow * 64 + scg * 8;
  const unsigned short* Ks1 = K + (size_t)(srow + 32) * 64 + scg * 8;
  const unsigned short* Vs0 = V + (size_t)srow * 2048 + scg * 8;
  const unsigned short* Vs1 = V + (size_t)(srow + 32) * 2048 + scg * 8;

#define STAGE_K(bf, kt0)                                   \
  do {                                                     \
    gload16(Ks0 + (size_t)(kt0) * 64, &lk[bf][tid * 8]);   \
    gload16(Ks1 + (size_t)(kt0) * 64, &lk[bf][(tid + 256) * 8]); \
  } while (0)
#define STAGE_V(bf, kt0)                                   \
  do {                                                     \
    gload16(Vs0 + (kt0), &lv[bf][tid * 8]);                \
    gload16(Vs1 + (kt0), &lv[bf][(tid + 256) * 8]);        \
  } while (0)

  f32x4 oacc[2][4];
#pragma unroll
  for (int s = 0; s < 2; ++s)
#pragma unroll
    for (int db = 0; db < 4; ++db) oacc[s][db] = (f32x4){0.f, 0.f, 0.f, 0.f};
  float lrun[2] = {0.f, 0.f};

  float* __restrict__ atile = attns + ((size_t)hb * 2048 + q0) * 2048;
  unsigned char* __restrict__ Pw = &pscr[wv][0];

  STAGE_K(0, 0);
  STAGE_V(0, 0);
  TILE_BARRIER(0);
  for (int p = 0; p < 64; ++p) {
    const int tl = p & 31;
    const int buf = p & 1;
    const int i = tl & 1;  // tile slot within pair
    if (p < 63) {
      const int nt_ = ((p + 1) & 31) * 64;
      STAGE_K(buf ^ 1, nt_);
      STAGE_V(buf ^ 1, nt_);
    }
    const bool s2 = (isA == (p < 32));  // this wave runs sweep2 this pass
    bool flushed = false;
    if (s2) {
      // QK^T + exp2 -> P scratch slab (i*2+s)
#pragma unroll
      for (int sub = 0; sub < 4; ++sub) {
        const int row = sub * 16 + lq;
        const int c0 = g ^ (row & 7);
        const unsigned short* lp = &lk[buf][row * 64];
        short8 ka0 = *reinterpret_cast<const short8*>(lp + c0 * 8);
        short8 ka1 = *reinterpret_cast<const short8*>(lp + (c0 ^ 4) * 8);
        const int cw = ((sub * 2 + (g >> 1)) ^ (lq & 7)) * 16 + (g & 1) * 8;
#pragma unroll
        for (int s = 0; s < 2; ++s) {
          f32x4 sa = (f32x4){0.f, 0.f, 0.f, 0.f};
          sa = MFMA16(ka0, bq[s][0], sa);
          sa = MFMA16(ka1, bq[s][1], sa);
          uint2 pr;
          pr.x = pack2bf(EXP2F(sa[0] - cfin[s]), EXP2F(sa[1] - cfin[s]));
          pr.y = pack2bf(EXP2F(sa[2] - cfin[s]), EXP2F(sa[3] - cfin[s]));
          *reinterpret_cast<uint2*>(Pw + ((i * 2 + s) * 16 + lq) * 128 + cw) = pr;
        }
      }
      // flush tile pair on odd i: 16 insts, each 2 rows x 512 B contiguous
      if (i == 1) {
        flushed = true;
        const int rlo = lane >> 5;        // row within pair
        const int it = (lane >> 4) & 1;   // source tile
        const int c16 = lane & 15;        // 16B-f32 chunk within tile
#pragma unroll
        for (int s = 0; s < 2; ++s) {
#pragma unroll
          for (int ri = 0; ri < 8; ++ri) {
            const int rr = ri * 2 + rlo;
            const int cr = ((c16 >> 1) ^ (rr & 7)) * 16 + (c16 & 1) * 8;
            const uint2 w = *reinterpret_cast<const uint2*>(
                Pw + ((it * 2 + s) * 16 + rr) * 128 + cr);
            f32x4 f4;
            f4[0] = __uint_as_float(w.x << 16);
            f4[1] = __uint_as_float(w.x & 0xffff0000u);
            f4[2] = __uint_as_float(w.y << 16);
            f4[3] = __uint_as_float(w.y & 0xffff0000u);
            float* dst = atile + (size_t)(s * 16 + rr) * 2048 +
                         (tl - 1) * 64 + (it * 16 + c16) * 4;
            __builtin_nontemporal_store(f4, reinterpret_cast<f32x4*>(dst));
          }
        }
      }
      // PV from this tile's slabs
#pragma unroll
      for (int ch = 0; ch < 2; ++ch) {
        const int cp = ((ch * 4 + g) ^ (lq & 7)) * 16;
        short8 pb0 = *reinterpret_cast<const short8*>(Pw + (i * 2 + 0) * 2048 + lq * 128 + cp);
        short8 pb1 = *reinterpret_cast<const short8*>(Pw + (i * 2 + 1) * 2048 + lq * 128 + cp);
#pragma unroll
        for (int db = 0; db < 4; ++db) {
          const int row = db * 16 + lq;
          const int cv = (ch * 4 + g) ^ (row & 7);
          short8 va = *reinterpret_cast<const short8*>(&lv[buf][row * 64 + cv * 8]);
          oacc[0][db] = MFMA16(va, pb0, oacc[0][db]);
          oacc[1][db] = MFMA16(va, pb1, oacc[1][db]);
        }
      }
    } else if (!isA) {
      // B-wave sweep1 (passes 0..31): denominator accumulation, no stores
#pragma unroll
      for (int sub = 0; sub < 4; ++sub) {
        const int row = sub * 16 + lq;
        const int c0 = g ^ (row & 7);
        const unsigned short* lp = &lk[buf][row * 64];
        short8 ka0 = *reinterpret_cast<const short8*>(lp + c0 * 8);
        short8 ka1 = *reinterpret_cast<const short8*>(lp + (c0 ^ 4) * 8);
#pragma unroll
        for (int s = 0; s < 2; ++s) {
          f32x4 sa = (f32x4){0.f, 0.f, 0.f, 0.f};
          sa = MFMA16(ka0, bq[s][0], sa);
          sa = MFMA16(ka1, bq[s][1], sa);
          lrun[s] += (EXP2F(sa[0]) + EXP2F(sa[1])) + (EXP2F(sa[2]) + EXP2F(sa[3]));
        }
      }
      if (p == 31) {
#pragma unroll
        for (int s = 0; s < 2; ++s) {
          float lc = lrun[s] + __shfl_xor(lrun[s], 16);
          lc += __shfl_xor(lc, 32);
          cfin[s] = LOG2F(lc);
        }
      }
    }
    if (p < 63) {
      if (flushed) { TILE_BARRIER(16); }  // 4 loads drain (oldest), 16 stores fly
      else         { TILE_BARRIER(0); }   // stores are >=1 pass old: paced out
    }
  }

  // epilogue: out^T tiles -> att_out[b][q][h*64+d] (bf16)
  const int h = hb >> 1, b_ = hb & 1;
#pragma unroll
  for (int s = 0; s < 2; ++s) {
    unsigned short* __restrict__ aob =
        att_out + ((size_t)(b_ * 2048 + q0 + s * 16 + lq)) * 1024 + h * 64;
#pragma unroll
    for (int db = 0; db < 4; ++db)
#pragma unroll
      for (int r = 0; r < 4; ++r)
        aob[db * 16 + g * 4 + r] = f2bf(oacc[s][db][r]);
  }
#undef STAGE_K
#undef STAGE_V
}

// ---- output projection: 64x128 tile, LDS double-buffered, bias fused ------
__global__ __launch_bounds__(256, 2) void k_oproj(
    const unsigned short* __restrict__ ao, const unsigned short* __restrict__ pw,
    const float* __restrict__ pb, float* __restrict__ out) {
  __shared__ unsigned short lA[2][4][64][8];   // 8 KB
  __shared__ unsigned short lB[2][4][128][8];  // 16 KB

  const int tid = threadIdx.x;
  const int wv = tid >> 6, lane = tid & 63, lq = lane & 15, g = lane >> 4;
  const int wr = wv >> 1, wc = wv & 1;
  const int m0 = blockIdx.x * 64;
  const int n0 = blockIdx.y * 128;

  const int rowa = tid & 63, kga = tid >> 6;
  const unsigned short* srcA = ao + (size_t)(m0 + rowa) * 1024 + kga * 8;
  unsigned short* dstA = &lA[0][0][0][0] + tid * 8;
  const int rowb = tid & 127, kgb = tid >> 7;
  const unsigned short* srcB = pw + (size_t)(n0 + rowb) * 1024 + kgb * 8;
  unsigned short* dstB = &lB[0][0][0][0] + tid * 8;

#define STAGE(bf, kc)                                       \
  do {                                                      \
    gload16(srcA + (kc), dstA + (bf)*2048);                 \
    gload16(srcB + (kc), dstB + (bf)*4096);                 \
    gload16(srcB + (kc) + 16, dstB + (bf)*4096 + 2048);     \
  } while (0)

  f32x4 acc[2][4];
#pragma unroll
  for (int i = 0; i < 2; ++i)
#pragma unroll
    for (int j = 0; j < 4; ++j) acc[i][j] = (f32x4){0.f, 0.f, 0.f, 0.f};

  STAGE(0, 0);
  __syncthreads();
  for (int t = 0; t < 32; ++t) {
    const int buf = t & 1;
    if (t < 31) STAGE(buf ^ 1, (t + 1) * 32);
    short8 a[2], b[4];
#pragma unroll
    for (int i = 0; i < 2; ++i)
      a[i] = *reinterpret_cast<const short8*>(&lA[buf][g][wr * 32 + i * 16 + lq][0]);
#pragma unroll
    for (int j = 0; j < 4; ++j)
      b[j] = *reinterpret_cast<const short8*>(&lB[buf][g][wc * 64 + j * 16 + lq][0]);
#pragma unroll
    for (int i = 0; i < 2; ++i)
#pragma unroll
      for (int j = 0; j < 4; ++j) acc[i][j] = MFMA16(a[i], b[j], acc[i][j]);
    __syncthreads();
  }
#undef STAGE

#pragma unroll
  for (int i = 0; i < 2; ++i) {
#pragma unroll
    for (int j = 0; j < 4; ++j) {
      const int n = n0 + wc * 64 + j * 16 + lq;
      const float bias = pb[n];
#pragma unroll
      for (int r = 0; r < 4; ++r) {
        const int m = m0 + wr * 32 + i * 16 + g * 4 + r;
        out[(size_t)m * 1024 + n] = acc[i][j][r] + bias;
      }
    }
  }
}

extern "C" void kernel_launch(void* const* d_in, const int* in_sizes, int n_in,
                              void* d_out, int out_size, void* d_ws, size_t ws_size,
                              hipStream_t stream) {
  const float* q = (const float*)d_in[0];
  const float* k = (const float*)d_in[1];
  const float* v = (const float*)d_in[2];
  const float* w_qs = (const float*)d_in[3];
  const float* w_ks = (const float*)d_in[4];
  const float* w_vs = (const float*)d_in[5];
  const float* proj_w = (const float*)d_in[6];
  const float* proj_b = (const float*)d_in[7];

  float* out = (float*)d_out;
  float* attns = out + (size_t)2 * 2048 * 1024;

  char* ws = (char*)d_ws;
  unsigned short* qb = (unsigned short*)(ws + ((size_t)0 << 20));
  unsigned short* kb = (unsigned short*)(ws + ((size_t)8 << 20));
  unsigned short* vb = (unsigned short*)(ws + ((size_t)16 << 20));
  unsigned short* wqt = (unsigned short*)(ws + ((size_t)24 << 20));
  unsigned short* wkt = (unsigned short*)(ws + ((size_t)26 << 20));
  unsigned short* wvt = (unsigned short*)(ws + ((size_t)28 << 20));
  unsigned short* pwb = (unsigned short*)(ws + ((size_t)30 << 20));
  unsigned short* qsb = (unsigned short*)(ws + ((size_t)32 << 20));
  unsigned short* ksb = (unsigned short*)(ws + ((size_t)40 << 20));
  unsigned short* vstb = (unsigned short*)(ws + ((size_t)48 << 20));
  unsigned short* aob = (unsigned short*)(ws + ((size_t)56 << 20));
  float* cfb = (float*)(ws + ((size_t)72 << 20));  // 32*2048 f32 = 256 KB

  k_pre<<<14080, 256, 0, stream>>>(q, k, v, proj_w, qb, kb, vb, pwb,
                                   w_qs, w_ks, w_vs, wqt, wkt, wvt);
  k_proj<<<dim3(32, 8, 3), 256, 0, stream>>>(qb, kb, vb, wqt, wkt, wvt, qsb, ksb, vstb);
  k_attn1<<<dim3(256), 256, 0, stream>>>(qsb, ksb, cfb);
  k_attn2<<<dim3(512), 256, 0, stream>>>(qsb, ksb, vstb, cfb, attns, aob);
  k_oproj<<<dim3(64, 8), 256, 0, stream>>>(aob, pwb, proj_b, out);
}